// Round 8
// baseline (411.490 us; speedup 1.0000x reference)
//
#include <hip/hip_runtime.h>
#include <hip/hip_bf16.h>
#include <stdint.h>

// ---------------------------------------------------------------------------
// SCINet forward (B=32,T=1024,C=128,HID=512, 3 levels, N_SPLITS=2) on gfx950.
// fp16 MFMA GEMMs, fp32 carry path, XOR bank-conflict swizzle baked into all
// producers (LDS staging stays linear, rule #21).
// R8: conv1 = R5 form (single-buffer, 128x64, 3 blk/CU -- proven optimum).
//     conv2 retiled 64x64 (wave 32x32) with B double-buffered 2-phase:
//     prefetch next B before compute, occupancy preserved at 3 blk/CU.
// ---------------------------------------------------------------------------

static constexpr int B_ = 32, T_ = 1024, C_ = 128, HID_ = 512;
static constexpr int K1_ = 5, K2_ = 3;

typedef __attribute__((ext_vector_type(8))) _Float16 half8;
typedef __attribute__((ext_vector_type(4))) float f32x4;

__device__ __forceinline__ unsigned short f2h(float f) {
    _Float16 h = (_Float16)f;                     // v_cvt_f16_f32 (RNE)
    return __builtin_bit_cast(unsigned short, h);
}

__device__ __forceinline__ void gload16(const void* g, void* l) {
    __builtin_amdgcn_global_load_lds(
        (const __attribute__((address_space(1))) unsigned int*)g,
        (__attribute__((address_space(3))) unsigned int*)l, 16, 0, 0);
}

// ---------------------------------------------------------------------------
// Weight prep: fp32 [slab][CIN][COUT] -> fp16 [slab][COUT][swz(CIN)].
// Two sources (mul/add) in one launch. Swizzle key = co&7 within each
// 128-element ci chunk: ci' = (ci & ~127) | ((ci&127) ^ ((co&7)<<3)).
// ---------------------------------------------------------------------------
template<int CIN, int COUT>
__global__ __launch_bounds__(256)
void wprep_k(const float* __restrict__ win1, unsigned short* __restrict__ wout1,
             const float* __restrict__ win2, unsigned short* __restrict__ wout2,
             int nhalf) {
    constexpr int TA = CIN / 64, TB = COUT / 64;
    int blk = blockIdx.x;
    int tb = blk % TB;
    int ta = (blk / TB) % TA;
    int s  = blk / (TA * TB);
    const float* win;
    unsigned short* wout;
    if (s < nhalf) { win = win1; wout = wout1; }
    else           { win = win2; wout = wout2; s -= nhalf; }
    __shared__ float tile[64][65];
    const float* src = win + (size_t)s * CIN * COUT;
    unsigned short* dst = wout + (size_t)s * CIN * COUT;
    int cl = threadIdx.x & 63;
    int rw = threadIdx.x >> 6;
    for (int r = rw; r < 64; r += 4)
        tile[r][cl] = src[(size_t)(ta * 64 + r) * COUT + tb * 64 + cl];
    __syncthreads();
    for (int r = rw; r < 64; r += 4) {
        int co = tb * 64 + r;
        int ci = ta * 64 + cl;
        int ciw = (ci & ~127) | ((ci & 127) ^ ((co & 7) << 3));
        dst[(size_t)co * CIN + ciw] = f2h(tile[cl][r]);
    }
}

// ---------------------------------------------------------------------------
// Split (level 0 only): x [B][1024][C] fp32 -> actb [2][B][512][swz(C)] fp16.
// actb swizzle key = (u+4)&7  (conv1 LDS row = u - t0 + 4, t0 % 8 == 0).
// ---------------------------------------------------------------------------
__global__ __launch_bounds__(256)
void split_k(const float* __restrict__ cur, unsigned short* __restrict__ outb,
             int Ls) {
    int idx = blockIdx.x * 256 + threadIdx.x;       // 1,048,576 total (rows*32)
    int row = idx >> 5;
    int cq  = (idx & 31) << 2;
    int BLs = B_ * Ls;
    int g  = row / BLs;
    int r2 = row - g * BLs;
    int b  = r2 / Ls;
    int u  = r2 - b * Ls;
    int p = g >> 1, i = g & 1;
    const float4 v = *(const float4*)(cur +
        ((size_t)(p * B_ + b) * (2 * Ls) + 2 * u + i) * C_ + cq);
    ushort4 o;
    o.x = f2h(v.x); o.y = f2h(v.y); o.z = f2h(v.z); o.w = f2h(v.w);
    int cqw = cq ^ (((u + 4) & 7) << 3);            // 8B-aligned XOR (bits 3-5)
    *(ushort4*)(outb + (size_t)row * C_ + cqw) = o;
}

// ---------------------------------------------------------------------------
// conv1 (R5 proven form): out = leaky( conv_K5( actb[g^1], W ) + b1 )
// tile 128 rows x 64 cols, 4 waves (2r x 2c; wave 64x32).
// LDS: A [132][128] (33KB, staged once), B [64][128] (16KB) per tap.
// 49KB -> 3 blocks/CU. Reads XOR col with (row&7)<<3.
// Output hidb pre-swizzled for conv2 (key (t+2)&7).
// ---------------------------------------------------------------------------
__global__ __launch_bounds__(256, 3)
void conv1_k(const unsigned short* __restrict__ actb,
             const unsigned short* __restrict__ wT,   // [widx][5][512][128swz]
             const float* __restrict__ bias,          // [widx][512]
             unsigned short* __restrict__ hid,        // [G][B][Ls][512swz]
             const unsigned short* __restrict__ zp,
             int Ls, int RT, int idxbase) {
    __shared__ unsigned short smemA[132 * 128];
    __shared__ unsigned short smemB[64 * 128];

    const int tid = threadIdx.x;
    const int lane = tid & 63;
    const int w = tid >> 6;
    const int wr = w >> 1, wc = w & 1;

    int blk = blockIdx.x;
    const int ct = blk & 7;                       // 8 col tiles of 64
    int t1 = blk >> 3;
    const int rt = t1 % RT;
    const int g  = t1 / RT;
    const int n0 = ct * 64;
    const int rowstart = rt * 128;
    const int b  = rowstart / Ls;
    const int t0 = rowstart - b * Ls;

    const int gin  = g ^ 1;
    const int widx = (idxbase + (g >> 1)) * 2 + (g & 1);

    const char* inb = (const char*)(actb + (size_t)(gin * B_ + b) * Ls * C_);
    const char* wb  = (const char*)(wT + (size_t)widx * (K1_ * HID_ * C_));
    const float* bptr = bias + (size_t)widx * HID_;

    // stage A once: rows t0-4 .. t0+127 (132 rows x 256 B = 33 chunks of 1KB)
    for (int ch = w; ch < 33; ch += 4) {
        int q = ch * 1024 + lane * 16;
        int r = q >> 8;
        int cb = q & 255;
        int t = t0 - 4 + r;
        const char* src = (t >= 0) ? inb + (size_t)t * 256 + cb
                                   : (const char*)zp + cb;
        gload16(src, (char*)smemA + ch * 1024);
    }

    f32x4 acc[4][2];
#pragma unroll
    for (int m = 0; m < 4; ++m)
#pragma unroll
        for (int n = 0; n < 2; ++n) acc[m][n] = (f32x4){0.f, 0.f, 0.f, 0.f};

    for (int kk = 0; kk < K1_; ++kk) {
        if (kk) __syncthreads();   // all waves done reading previous B tile
        const char* wt = wb + (size_t)kk * HID_ * C_ * 2;
        // B tile: 64 co rows x 256B = 16 chunks of 1KB
        for (int ch = w; ch < 16; ch += 4) {
            int q = ch * 1024 + lane * 16;
            int co = q >> 8;
            int cb = q & 255;
            gload16(wt + (size_t)(n0 + co) * 256 + cb, (char*)smemB + ch * 1024);
        }
        asm volatile("s_waitcnt vmcnt(0)" ::: "memory");
        __syncthreads();

#pragma unroll
        for (int ks = 0; ks < 4; ++ks) {
            half8 aF[4], bF[2];
            const int cole = ks * 32 + ((lane >> 4) << 3);
#pragma unroll
            for (int m = 0; m < 4; ++m) {
                int ar = kk + wr * 64 + m * 16 + (lane & 15);
                aF[m] = *(const half8*)(smemA + ar * 128 + (cole ^ ((ar & 7) << 3)));
            }
#pragma unroll
            for (int n = 0; n < 2; ++n) {
                int br = wc * 32 + n * 16 + (lane & 15);
                bF[n] = *(const half8*)(smemB + br * 128 + (cole ^ ((br & 7) << 3)));
            }
#pragma unroll
            for (int m = 0; m < 4; ++m) {
                acc[m][0] = __builtin_amdgcn_mfma_f32_16x16x32_f16(
                    aF[m], bF[0], acc[m][0], 0, 0, 0);
                acc[m][1] = __builtin_amdgcn_mfma_f32_16x16x32_f16(
                    aF[m], bF[1], acc[m][1], 0, 0, 0);
            }
        }
    }

    unsigned short* outp = hid + ((size_t)(g * B_ + b) * Ls + t0) * HID_;
#pragma unroll
    for (int n = 0; n < 2; ++n) {
        int co = n0 + wc * 32 + n * 16 + (lane & 15);
        float bv = bptr[co];
#pragma unroll
        for (int m = 0; m < 4; ++m) {
            int u0 = wr * 64 + m * 16 + ((lane >> 4) << 2);
#pragma unroll
            for (int q = 0; q < 4; ++q) {
                float v = acc[m][n][q] + bv;
                v = (v > 0.f) ? v : 0.01f * v;            // LeakyReLU
                int t = t0 + u0 + q;
                int cow = (co & ~127) | ((co & 127) ^ (((t + 2) & 7) << 3));
                outp[(size_t)(u0 + q) * HID_ + cow] = f2h(v);
            }
        }
    }
}

// ---------------------------------------------------------------------------
// conv2: s = tanh( causal_conv_K3( hid[g], W2[widx] ) + b2[widx] )
// R8: tile 64 rows x 64 cols, 4 waves (2x2, wave 32x32). B double-buffered
// 2x[64][128] (prefetch next (ck,kk) before compute); A [66][128] single-
// buffered, refilled once per ck. LDS 49.7KB -> 3 blocks/CU.
// EPI 0 (gate):  mul = cur[p][b][2u+i][c] * exp(s) -> mulf (f32) + actb (fp16)
// EPI 1 (mid):   val = mulf +/- s -> nxt (f32) + next-level actb (fused split)
// EPI 2 (last):  val = mulf +/- s -> d_out[b][tau][c], tau = u | revbits(g)
// ---------------------------------------------------------------------------
template<int EPI>
__global__ __launch_bounds__(256, 3)
void conv2_k(const unsigned short* __restrict__ hid,
             const unsigned short* __restrict__ wT,   // [widx][3][128][512swz]
             const float* __restrict__ bias,          // [widx][128]
             const float* __restrict__ cur,           // EPI==0
             float* __restrict__ mulf,
             unsigned short* __restrict__ actb,       // EPI==0: gate out (swz)
             float* __restrict__ nxt,                 // EPI==1 out
             unsigned short* __restrict__ actn,       // EPI==1: next-lvl actb
             float* __restrict__ dout,                // EPI==2 out
             const unsigned short* __restrict__ zp,
             int Ls, int RT, int idxbase) {
    __shared__ unsigned short smemA[66 * 128];
    __shared__ unsigned short smemB[2][64 * 128];

    const int tid = threadIdx.x;
    const int lane = tid & 63;
    const int w = tid >> 6;
    const int wr = w >> 1, wc = w & 1;

    int blk = blockIdx.x;
    const int ct = blk & 1;                       // 2 col tiles of 64
    int t1 = blk >> 1;
    const int rt = t1 % RT;
    const int g  = t1 / RT;
    const int n0 = ct * 64;
    const int rowstart = rt * 64;
    const int b  = rowstart / Ls;
    const int t0 = rowstart - b * Ls;
    const int widx = (idxbase + (g >> 1)) * 2 + (g & 1);

    const char* inb = (const char*)(hid + (size_t)(g * B_ + b) * Ls * HID_);
    const char* wb  = (const char*)(wT + (size_t)widx * (K2_ * C_ * HID_));
    const float* bptr = bias + (size_t)widx * C_;

    const int bq  = lane * 16;
    const int bco = bq >> 8;                      // co offset within 1KB chunk
    const int bcb = bq & 255;

    // stage A chunk ck: rows t0-2 .. t0+63 (66 rows x 256 B = 16896 B)
    auto stageA = [&](int ck) {
        for (int ch = w; ch < 17; ch += 4) {
            int q = ch * 1024 + lane * 16;
            if (q < 16896) {
                int r = q >> 8;
                int cb = q & 255;
                int t = t0 - 2 + r;
                const char* src = (t >= 0)
                    ? inb + (size_t)t * 1024 + ck * 256 + cb
                    : (const char*)zp + cb;
                gload16(src, (char*)smemA + ch * 1024);
            }
        }
    };
    // stage B tile (ck,kk): 64 co rows x 256 B = 16 chunks of 1KB
    auto stageB = [&](int ck, int kk, int buf) {
        const char* wt = wb + (size_t)kk * C_ * HID_ * 2;
#pragma unroll
        for (int ch0 = 0; ch0 < 4; ++ch0) {
            int ch = w + ch0 * 4;
            gload16(wt + (size_t)(n0 + ch * 4 + bco) * 1024 + ck * 256 + bcb,
                    (char*)smemB[buf] + ch * 1024);
        }
    };

    f32x4 acc[2][2];
#pragma unroll
    for (int m = 0; m < 2; ++m)
#pragma unroll
        for (int n = 0; n < 2; ++n) acc[m][n] = (f32x4){0.f, 0.f, 0.f, 0.f};

    stageB(0, 0, 0);
    stageA(0);
    asm volatile("s_waitcnt vmcnt(0)" ::: "memory");
    __syncthreads();

#pragma unroll
    for (int ck = 0; ck < 4; ++ck) {
#pragma unroll
        for (int kk = 0; kk < K2_; ++kk) {
            const int r = ck * 3 + kk;
            // phase 1: prefetch next B tile into the other buffer
            if (r < 11) {
                if (kk < 2) stageB(ck, kk + 1, (r + 1) & 1);
                else        stageB(ck + 1, 0, (r + 1) & 1);
            }
            // phase 2: compute current round from smemB[r&1]
            const unsigned short* sB = smemB[r & 1];
#pragma unroll
            for (int ks = 0; ks < 4; ++ks) {
                half8 aF[2], bF[2];
                const int cole = ks * 32 + ((lane >> 4) << 3);
#pragma unroll
                for (int m = 0; m < 2; ++m) {
                    int ar = kk + wr * 32 + m * 16 + (lane & 15);
                    aF[m] = *(const half8*)(smemA + ar * 128 + (cole ^ ((ar & 7) << 3)));
                }
#pragma unroll
                for (int n = 0; n < 2; ++n) {
                    int br = wc * 32 + n * 16 + (lane & 15);
                    bF[n] = *(const half8*)(sB + br * 128 + (cole ^ ((br & 7) << 3)));
                }
#pragma unroll
                for (int m = 0; m < 2; ++m)
#pragma unroll
                    for (int n = 0; n < 2; ++n)
                        acc[m][n] = __builtin_amdgcn_mfma_f32_16x16x32_f16(
                            aF[m], bF[n], acc[m][n], 0, 0, 0);
            }
            // phase 3: make next buffers resident
            if (r < 11) {
                if (kk == 2) {
                    __syncthreads();          // all waves done reading A(ck)
                    stageA(ck + 1);           // refill A (exposed drain, 4x/blk)
                }
                asm volatile("s_waitcnt vmcnt(0)" ::: "memory");
                __syncthreads();
            }
        }
    }

    const size_t rowb = (size_t)(g * B_ + b) * Ls + t0;
    const int p_ = g >> 1, i_ = g & 1;
    const int Ls2 = Ls >> 1;
#pragma unroll
    for (int n = 0; n < 2; ++n) {
        int c = n0 + wc * 32 + n * 16 + (lane & 15);
        float bv = bptr[c];
#pragma unroll
        for (int m = 0; m < 2; ++m) {
            int u0 = wr * 32 + m * 16 + ((lane >> 4) << 2);
#pragma unroll
            for (int q = 0; q < 4; ++q) {
                float v = acc[m][n][q] + bv;
                float xc = fminf(fmaxf(v, -15.f), 15.f);
                float e2 = __expf(2.f * xc);
                float th = (e2 - 1.f) / (e2 + 1.f);        // tanh
                size_t ro = rowb + (size_t)(u0 + q);
                int u = t0 + u0 + q;                       // local split time
                if (EPI == 0) {
                    float sv = cur[((size_t)(p_ * B_ + b) * (2 * Ls) + 2 * u + i_) * C_ + c];
                    float mv = sv * __expf(th);
                    mulf[ro * C_ + c] = mv;
                    int cw = c ^ (((u + 4) & 7) << 3);     // actb swizzle
                    actb[ro * C_ + cw] = f2h(mv);
                } else {
                    float mv = mulf[ro * C_ + c];
                    float val = (i_ == 0) ? (mv + th) : (mv - th);
                    if (EPI == 1) {
                        nxt[ro * C_ + c] = val;
                        // fused split for next level
                        int gq = g * 2 + (u & 1);
                        int uq = u >> 1;
                        int cw = c ^ (((uq + 4) & 7) << 3);
                        actn[((size_t)(gq * B_ + b) * Ls2 + uq) * C_ + cw] = f2h(val);
                    } else {
                        // fused rev_split gather (last level, Ls = 128)
                        int tau = u | (((g >> 2) & 1) << 7) | (((g >> 1) & 1) << 8)
                                    | ((g & 1) << 9);
                        dout[((size_t)b * T_ + tau) * C_ + c] = val;
                    }
                }
            }
        }
    }
}

// ---------------------------------------------------------------------------
extern "C" void kernel_launch(void* const* d_in, const int* in_sizes, int n_in,
                              void* d_out, int out_size, void* d_ws, size_t ws_size,
                              hipStream_t stream) {
    const float* x   = (const float*)d_in[0];
    const float* mw1 = (const float*)d_in[1];
    const float* mb1 = (const float*)d_in[2];
    const float* mw2 = (const float*)d_in[3];
    const float* mb2 = (const float*)d_in[4];
    const float* aw1 = (const float*)d_in[5];
    const float* ab1 = (const float*)d_in[6];
    const float* aw2 = (const float*)d_in[7];
    const float* ab2 = (const float*)d_in[8];

    char* ws = (char*)d_ws;
    size_t off = 0;
    auto alloc = [&](size_t sz) {
        char* p = ws + off;
        off += (sz + 255) & ~(size_t)255;
        return p;
    };
    unsigned short* zp   = (unsigned short*)alloc(8192);
    unsigned short* w1m  = (unsigned short*)alloc((size_t)14 * 5 * 512 * 128 * 2);
    unsigned short* w1a  = (unsigned short*)alloc((size_t)14 * 5 * 512 * 128 * 2);
    unsigned short* w2m  = (unsigned short*)alloc((size_t)14 * 3 * 128 * 512 * 2);
    unsigned short* w2a  = (unsigned short*)alloc((size_t)14 * 3 * 128 * 512 * 2);
    float* bufA          = (float*)alloc((size_t)4194304 * 4);
    float* bufB          = (float*)alloc((size_t)4194304 * 4);
    unsigned short* actb = (unsigned short*)alloc((size_t)4194304 * 2);
    unsigned short* hidb = (unsigned short*)alloc((size_t)16777216 * 2);
    float* mulf          = (float*)alloc((size_t)4194304 * 4);
    (void)ws_size; (void)n_in; (void)in_sizes; (void)out_size;

    hipMemsetAsync(zp, 0, 8192, stream);

    // weight prep: transpose + fp16 + bank-conflict swizzle (2 launches)
    wprep_k<128, 512><<<2240, 256, 0, stream>>>(mw1, w1m, aw1, w1a, 70);
    wprep_k<512, 128><<<1344, 256, 0, stream>>>(mw2, w2m, aw2, w2a, 42);

    // level-0 split (levels 1,2 are fused into conv2-EPI1)
    split_k<<<4096, 256, 0, stream>>>(x, actb, 512);

    for (int lvl = 0; lvl < 3; ++lvl) {
        const int P = 1 << lvl;
        const int G = 2 * P;
        const int Ls = (1024 >> lvl) >> 1;
        const int idxbase = P - 1;
        const float* cur = (lvl == 0) ? x : ((lvl == 1) ? bufA : bufB);
        float* nxt = (lvl == 1) ? bufB : bufA;
        const int RT1 = Ls / 4;   // 128-row tiles: B*Ls/128
        const int RT2 = Ls / 2;   // 64-row tiles:  B*Ls/64

        conv1_k<<<G * RT1 * 8, 256, 0, stream>>>(actb, w1m, mb1, hidb, zp,
                                                 Ls, RT1, idxbase);
        conv2_k<0><<<G * RT2 * 2, 256, 0, stream>>>(hidb, w2m, mb2, cur, mulf,
                                                    actb, nullptr, nullptr, nullptr,
                                                    zp, Ls, RT2, idxbase);
        conv1_k<<<G * RT1 * 8, 256, 0, stream>>>(actb, w1a, ab1, hidb, zp,
                                                 Ls, RT1, idxbase);
        if (lvl < 2) {
            conv2_k<1><<<G * RT2 * 2, 256, 0, stream>>>(hidb, w2a, ab2, nullptr, mulf,
                                                        nullptr, nxt, actb, nullptr,
                                                        zp, Ls, RT2, idxbase);
        } else {
            conv2_k<2><<<G * RT2 * 2, 256, 0, stream>>>(hidb, w2a, ab2, nullptr, mulf,
                                                        nullptr, nullptr, nullptr,
                                                        (float*)d_out,
                                                        zp, Ls, RT2, idxbase);
        }
    }
}

// Round 9
// 368.701 us; speedup vs baseline: 1.1161x; 1.1161x over previous
//
#include <hip/hip_runtime.h>
#include <hip/hip_bf16.h>
#include <stdint.h>

// ---------------------------------------------------------------------------
// SCINet forward (B=32,T=1024,C=128,HID=512, 3 levels, N_SPLITS=2) on gfx950.
// fp16 MFMA GEMMs, fp32 carry path, XOR bank-conflict swizzle baked into all
// producers (LDS staging stays linear, rule #21).
// R9: conv1 = WEIGHT-STATIONARY. Each of 512 co-resident blocks loads its
// 64-col x 5-tap W1 slice into VGPRs ONCE (pre-loop, statically indexed ->
// cannot be sunk, unlike R6's in-loop loads), then sweeps 8 row-tiles of 64
// with A double-buffered in LDS (2x20KB). Counted vmcnt(21) keeps epilogue
// stores + next stage in flight -- zero exposed drain in steady state.
// conv2 = exact R5 form (single-variable change).
// ---------------------------------------------------------------------------

static constexpr int B_ = 32, T_ = 1024, C_ = 128, HID_ = 512;
static constexpr int K1_ = 5, K2_ = 3;

typedef __attribute__((ext_vector_type(8))) _Float16 half8;
typedef __attribute__((ext_vector_type(4))) float f32x4;

__device__ __forceinline__ unsigned short f2h(float f) {
    _Float16 h = (_Float16)f;                     // v_cvt_f16_f32 (RNE)
    return __builtin_bit_cast(unsigned short, h);
}

__device__ __forceinline__ void gload16(const void* g, void* l) {
    __builtin_amdgcn_global_load_lds(
        (const __attribute__((address_space(1))) unsigned int*)g,
        (__attribute__((address_space(3))) unsigned int*)l, 16, 0, 0);
}

// ---------------------------------------------------------------------------
// Weight prep: fp32 [slab][CIN][COUT] -> fp16 [slab][COUT][CIN].
// SWZ=true: XOR-swizzle ci within 128-chunks by co&7 (conv2, LDS-staged).
// SWZ=false: linear (conv1 loads weights straight to VGPRs).
// ---------------------------------------------------------------------------
template<int CIN, int COUT, bool SWZ>
__global__ __launch_bounds__(256)
void wprep_k(const float* __restrict__ win1, unsigned short* __restrict__ wout1,
             const float* __restrict__ win2, unsigned short* __restrict__ wout2,
             int nhalf) {
    constexpr int TA = CIN / 64, TB = COUT / 64;
    int blk = blockIdx.x;
    int tb = blk % TB;
    int ta = (blk / TB) % TA;
    int s  = blk / (TA * TB);
    const float* win;
    unsigned short* wout;
    if (s < nhalf) { win = win1; wout = wout1; }
    else           { win = win2; wout = wout2; s -= nhalf; }
    __shared__ float tile[64][65];
    const float* src = win + (size_t)s * CIN * COUT;
    unsigned short* dst = wout + (size_t)s * CIN * COUT;
    int cl = threadIdx.x & 63;
    int rw = threadIdx.x >> 6;
    for (int r = rw; r < 64; r += 4)
        tile[r][cl] = src[(size_t)(ta * 64 + r) * COUT + tb * 64 + cl];
    __syncthreads();
    for (int r = rw; r < 64; r += 4) {
        int co = tb * 64 + r;
        int ci = ta * 64 + cl;
        int ciw = SWZ ? ((ci & ~127) | ((ci & 127) ^ ((co & 7) << 3))) : ci;
        dst[(size_t)co * CIN + ciw] = f2h(tile[cl][r]);
    }
}

// ---------------------------------------------------------------------------
// Split (level 0 only): x [B][1024][C] fp32 -> actb [2][B][512][swz(C)] fp16.
// actb swizzle key = (u+4)&7  (conv1 LDS row = u - t0 + 4, t0 % 8 == 0).
// ---------------------------------------------------------------------------
__global__ __launch_bounds__(256)
void split_k(const float* __restrict__ cur, unsigned short* __restrict__ outb,
             int Ls) {
    int idx = blockIdx.x * 256 + threadIdx.x;       // 1,048,576 total (rows*32)
    int row = idx >> 5;
    int cq  = (idx & 31) << 2;
    int BLs = B_ * Ls;
    int g  = row / BLs;
    int r2 = row - g * BLs;
    int b  = r2 / Ls;
    int u  = r2 - b * Ls;
    int p = g >> 1, i = g & 1;
    const float4 v = *(const float4*)(cur +
        ((size_t)(p * B_ + b) * (2 * Ls) + 2 * u + i) * C_ + cq);
    ushort4 o;
    o.x = f2h(v.x); o.y = f2h(v.y); o.z = f2h(v.z); o.w = f2h(v.w);
    int cqw = cq ^ (((u + 4) & 7) << 3);            // 8B-aligned XOR (bits 3-5)
    *(ushort4*)(outb + (size_t)row * C_ + cqw) = o;
}

// ---------------------------------------------------------------------------
// conv1 (weight-stationary): out = leaky( conv_K5( actb[g^1], W ) + b1 )
// 512 blocks (2/CU, all resident): block = (g, rsplit, ct); owns 64 cols.
// B (5 taps x 64 cols x 128 cin) in VGPRs: breg[5][2][4] half8 = 160 VGPR,
// loaded once pre-loop (statically indexed). A: 2 x [80][128] LDS dbuf.
// Loop over 8 row-tiles of 64: [A]barrier; stage(rt+1); vmcnt(21);
// [B]barrier; 80 MFMA + 40 ds_read; 16 stores. Waves 2x2, wave tile 32x32.
// Output hidb pre-swizzled for conv2 (key (t+2)&7).
// ---------------------------------------------------------------------------
__global__ __launch_bounds__(256, 2)
void conv1_k(const unsigned short* __restrict__ actb,
             const unsigned short* __restrict__ wL,   // [widx][5][512][128] LINEAR
             const float* __restrict__ bias,          // [widx][512]
             unsigned short* __restrict__ hid,        // [G][B][Ls][512swz]
             const unsigned short* __restrict__ zp,
             int Ls, int rsplit, int idxbase) {
    __shared__ unsigned short smemA[2][80 * 128];     // 2 x 20 KiB

    const int tid = threadIdx.x;
    const int lane = tid & 63;
    const int w = tid >> 6;
    const int wr = w >> 1, wc = w & 1;

    const int blk = blockIdx.x;
    const int ct = blk & 7;                           // 8 col tiles of 64
    const int rs = (blk >> 3) % rsplit;
    const int g  = (blk >> 3) / rsplit;
    const int n0 = ct * 64;
    const int gin  = g ^ 1;
    const int widx = (idxbase + (g >> 1)) * 2 + (g & 1);

    const char* gbase = (const char*)(actb + (size_t)gin * B_ * Ls * C_);
    const float* bptr = bias + (size_t)widx * HID_;

    // ---- load B slice into registers: breg[tap][n][ks] (40 half8) ----
    const unsigned short* wlane = wL + (size_t)widx * (K1_ * HID_ * C_)
        + (size_t)(n0 + wc * 32 + (lane & 15)) * C_ + ((lane >> 4) << 3);
    half8 breg[K1_][2][4];
#pragma unroll
    for (int t = 0; t < K1_; ++t)
#pragma unroll
        for (int n = 0; n < 2; ++n)
#pragma unroll
            for (int ks = 0; ks < 4; ++ks)
                breg[t][n][ks] = *(const half8*)(wlane
                    + ((size_t)t * HID_ + n * 16) * C_ + ks * 32);

    // bias (hoisted: no vmem loads inside the rt loop -> vmcnt counts stay exact)
    const float bv0 = bptr[n0 + wc * 32 + (lane & 15)];
    const float bv1 = bptr[n0 + wc * 32 + 16 + (lane & 15)];

    const int rtbase = rs * 8;

    // stage one 64-row tile (+halo) into buf p: 20 chunks of 1KB, 5 per wave
    auto stage = [&](int rt, int p) {
        const int b  = (rt * 64) / Ls;
        const int t0 = (rt * 64) % Ls;
        const char* inb = gbase + (size_t)b * Ls * 256;
#pragma unroll
        for (int j = 0; j < 5; ++j) {
            int ch = w * 5 + j;
            int q = ch * 1024 + lane * 16;
            int r = q >> 8;
            int cb = q & 255;
            int t = t0 - 4 + r;
            const char* src = (t >= 0) ? inb + (size_t)t * 256 + cb
                                       : (const char*)zp + cb;
            gload16(src, (char*)smemA[p] + ch * 1024);
        }
    };

    stage(rtbase, 0);
    asm volatile("s_waitcnt vmcnt(0)" ::: "memory");  // breg + buf0 + bias ready
    __syncthreads();

#pragma unroll
    for (int i = 0; i < 8; ++i) {
        const int rt = rtbase + i;
        const int b  = (rt * 64) / Ls;
        const int t0 = (rt * 64) % Ls;
        const int p  = i & 1;

        __syncthreads();                  // [A] all waves done reading buf[p^1]
        if (i < 7) stage(rt + 1, p ^ 1);  // 5 gload16 -> freed buffer
        if (i > 0) {
            if (i < 7) {
                // outstanding: stage(i)[5] + stores(i-1)[16] + stage(i+1)[5]
                asm volatile("s_waitcnt vmcnt(21)" ::: "memory");
            } else {
                // no new stage issued: stage(7)[5] + stores[16] -> force 5 oldest
                asm volatile("s_waitcnt vmcnt(16)" ::: "memory");
            }
            __syncthreads();              // [B] buf[p] fully staged for everyone
        }

        f32x4 acc[2][2];
#pragma unroll
        for (int m = 0; m < 2; ++m)
#pragma unroll
            for (int n = 0; n < 2; ++n) acc[m][n] = (f32x4){0.f, 0.f, 0.f, 0.f};

        const unsigned short* sA = smemA[p];
#pragma unroll
        for (int kk = 0; kk < K1_; ++kk) {
#pragma unroll
            for (int ks = 0; ks < 4; ++ks) {
                half8 aF[2];
                const int cole = ks * 32 + ((lane >> 4) << 3);
#pragma unroll
                for (int m = 0; m < 2; ++m) {
                    int ar = kk + wr * 32 + m * 16 + (lane & 15);
                    aF[m] = *(const half8*)(sA + ar * 128 + (cole ^ ((ar & 7) << 3)));
                }
#pragma unroll
                for (int m = 0; m < 2; ++m) {
                    acc[m][0] = __builtin_amdgcn_mfma_f32_16x16x32_f16(
                        aF[m], breg[kk][0][ks], acc[m][0], 0, 0, 0);
                    acc[m][1] = __builtin_amdgcn_mfma_f32_16x16x32_f16(
                        aF[m], breg[kk][1][ks], acc[m][1], 0, 0, 0);
                }
            }
        }

        // epilogue: exactly 16 global 2B stores per thread (counted in vmcnt)
        unsigned short* outp = hid + ((size_t)(g * B_ + b) * Ls + t0) * HID_;
#pragma unroll
        for (int n = 0; n < 2; ++n) {
            const int co = n0 + wc * 32 + n * 16 + (lane & 15);
            const float bv = n ? bv1 : bv0;
#pragma unroll
            for (int m = 0; m < 2; ++m) {
                const int u0 = wr * 32 + m * 16 + ((lane >> 4) << 2);
#pragma unroll
                for (int q = 0; q < 4; ++q) {
                    float v = acc[m][n][q] + bv;
                    v = (v > 0.f) ? v : 0.01f * v;        // LeakyReLU
                    int t = t0 + u0 + q;
                    int cow = (co & ~127) | ((co & 127) ^ (((t + 2) & 7) << 3));
                    outp[(size_t)(u0 + q) * HID_ + cow] = f2h(v);
                }
            }
        }
    }
}

// ---------------------------------------------------------------------------
// conv2 (exact R5 form): s = tanh( causal_conv_K3( hid[g], W2 ) + b2 )
// EPI 0 (gate):  mul = cur[p][b][2u+i][c] * exp(s) -> mulf (f32) + actb (fp16)
// EPI 1 (mid):   val = mulf +/- s -> nxt (f32) + next-level actb (fused split)
// EPI 2 (last):  val = mulf +/- s -> d_out[b][tau][c], tau = u | revbits(g)
// tile 64 rows x 128 cols, 4 waves (2x2, wave tile 32x64), K = 3*512 chunked.
// LDS 49KB -> 3 blocks/CU.
// ---------------------------------------------------------------------------
template<int EPI>
__global__ __launch_bounds__(256, 3)
void conv2_k(const unsigned short* __restrict__ hid,
             const unsigned short* __restrict__ wT,   // [widx][3][128][512swz]
             const float* __restrict__ bias,          // [widx][128]
             const float* __restrict__ cur,           // EPI==0
             float* __restrict__ mulf,
             unsigned short* __restrict__ actb,       // EPI==0: gate out (swz)
             float* __restrict__ nxt,                 // EPI==1 out
             unsigned short* __restrict__ actn,       // EPI==1: next-lvl actb
             float* __restrict__ dout,                // EPI==2 out
             const unsigned short* __restrict__ zp,
             int Ls, int RT, int idxbase) {
    __shared__ unsigned short smemA[66 * 128];
    __shared__ unsigned short smemB[128 * 128];

    const int tid = threadIdx.x;
    const int lane = tid & 63;
    const int w = tid >> 6;
    const int wr = w >> 1, wc = w & 1;

    int blk = blockIdx.x;
    const int rt = blk % RT;
    const int g  = blk / RT;
    const int rowstart = rt * 64;
    const int b  = rowstart / Ls;
    const int t0 = rowstart - b * Ls;
    const int widx = (idxbase + (g >> 1)) * 2 + (g & 1);

    const char* inb = (const char*)(hid + (size_t)(g * B_ + b) * Ls * HID_);
    const char* wb  = (const char*)(wT + (size_t)widx * (K2_ * C_ * HID_));
    const float* bptr = bias + (size_t)widx * C_;

    f32x4 acc[2][4];
#pragma unroll
    for (int m = 0; m < 2; ++m)
#pragma unroll
        for (int n = 0; n < 4; ++n) acc[m][n] = (f32x4){0.f, 0.f, 0.f, 0.f};

    for (int ck = 0; ck < 4; ++ck) {           // 4 chunks of 128 over CIN=512
        if (ck) __syncthreads();
        // stage A chunk: rows t0-2 .. t0+63 (66 rows x 256 B = 16896 B)
        for (int ch = w; ch < 17; ch += 4) {
            int q = ch * 1024 + lane * 16;
            if (q < 16896) {
                int r = q >> 8;
                int cb = q & 255;
                int t = t0 - 2 + r;
                const char* src = (t >= 0)
                    ? inb + (size_t)t * 1024 + ck * 256 + cb
                    : (const char*)zp + cb;
                gload16(src, (char*)smemA + ch * 1024);
            }
        }
        for (int kk = 0; kk < K2_; ++kk) {
            if (kk) __syncthreads();
            const char* wt = wb + (size_t)kk * C_ * HID_ * 2;
            for (int ch = w; ch < 32; ch += 4) {
                int q = ch * 1024 + lane * 16;
                int co = q >> 8;
                int cb = q & 255;
                gload16(wt + (size_t)co * 1024 + ck * 256 + cb,
                        (char*)smemB + ch * 1024);
            }
            asm volatile("s_waitcnt vmcnt(0)" ::: "memory");
            __syncthreads();

#pragma unroll
            for (int ks = 0; ks < 4; ++ks) {
                half8 aF[2], bF[4];
                const int cole = ks * 32 + ((lane >> 4) << 3);
#pragma unroll
                for (int m = 0; m < 2; ++m) {
                    int ar = kk + wr * 32 + m * 16 + (lane & 15);
                    aF[m] = *(const half8*)(smemA + ar * 128 + (cole ^ ((ar & 7) << 3)));
                }
#pragma unroll
                for (int n = 0; n < 4; ++n) {
                    int br = wc * 64 + n * 16 + (lane & 15);
                    bF[n] = *(const half8*)(smemB + br * 128 + (cole ^ ((br & 7) << 3)));
                }
#pragma unroll
                for (int m = 0; m < 2; ++m)
#pragma unroll
                    for (int n = 0; n < 4; ++n)
                        acc[m][n] = __builtin_amdgcn_mfma_f32_16x16x32_f16(
                            aF[m], bF[n], acc[m][n], 0, 0, 0);
            }
        }
    }

    const size_t rowb = (size_t)(g * B_ + b) * Ls + t0;
    const int p_ = g >> 1, i_ = g & 1;
    const int Ls2 = Ls >> 1;
#pragma unroll
    for (int n = 0; n < 4; ++n) {
        int c = wc * 64 + n * 16 + (lane & 15);
        float bv = bptr[c];
#pragma unroll
        for (int m = 0; m < 2; ++m) {
            int u0 = wr * 32 + m * 16 + ((lane >> 4) << 2);
#pragma unroll
            for (int q = 0; q < 4; ++q) {
                float v = acc[m][n][q] + bv;
                float xc = fminf(fmaxf(v, -15.f), 15.f);
                float e2 = __expf(2.f * xc);
                float th = (e2 - 1.f) / (e2 + 1.f);        // tanh
                size_t ro = rowb + (size_t)(u0 + q);
                int u = t0 + u0 + q;                       // local split time
                if (EPI == 0) {
                    float sv = cur[((size_t)(p_ * B_ + b) * (2 * Ls) + 2 * u + i_) * C_ + c];
                    float mv = sv * __expf(th);
                    mulf[ro * C_ + c] = mv;
                    int cw = c ^ (((u + 4) & 7) << 3);     // actb swizzle
                    actb[ro * C_ + cw] = f2h(mv);
                } else {
                    float mv = mulf[ro * C_ + c];
                    float val = (i_ == 0) ? (mv + th) : (mv - th);
                    if (EPI == 1) {
                        nxt[ro * C_ + c] = val;
                        // fused split for next level
                        int gq = g * 2 + (u & 1);
                        int uq = u >> 1;
                        int cw = c ^ (((uq + 4) & 7) << 3);
                        actn[((size_t)(gq * B_ + b) * Ls2 + uq) * C_ + cw] = f2h(val);
                    } else {
                        // fused rev_split gather (last level, Ls = 128)
                        int tau = u | (((g >> 2) & 1) << 7) | (((g >> 1) & 1) << 8)
                                    | ((g & 1) << 9);
                        dout[((size_t)b * T_ + tau) * C_ + c] = val;
                    }
                }
            }
        }
    }
}

// ---------------------------------------------------------------------------
extern "C" void kernel_launch(void* const* d_in, const int* in_sizes, int n_in,
                              void* d_out, int out_size, void* d_ws, size_t ws_size,
                              hipStream_t stream) {
    const float* x   = (const float*)d_in[0];
    const float* mw1 = (const float*)d_in[1];
    const float* mb1 = (const float*)d_in[2];
    const float* mw2 = (const float*)d_in[3];
    const float* mb2 = (const float*)d_in[4];
    const float* aw1 = (const float*)d_in[5];
    const float* ab1 = (const float*)d_in[6];
    const float* aw2 = (const float*)d_in[7];
    const float* ab2 = (const float*)d_in[8];

    char* ws = (char*)d_ws;
    size_t off = 0;
    auto alloc = [&](size_t sz) {
        char* p = ws + off;
        off += (sz + 255) & ~(size_t)255;
        return p;
    };
    unsigned short* zp   = (unsigned short*)alloc(8192);
    unsigned short* w1m  = (unsigned short*)alloc((size_t)14 * 5 * 512 * 128 * 2);
    unsigned short* w1a  = (unsigned short*)alloc((size_t)14 * 5 * 512 * 128 * 2);
    unsigned short* w2m  = (unsigned short*)alloc((size_t)14 * 3 * 128 * 512 * 2);
    unsigned short* w2a  = (unsigned short*)alloc((size_t)14 * 3 * 128 * 512 * 2);
    float* bufA          = (float*)alloc((size_t)4194304 * 4);
    float* bufB          = (float*)alloc((size_t)4194304 * 4);
    unsigned short* actb = (unsigned short*)alloc((size_t)4194304 * 2);
    unsigned short* hidb = (unsigned short*)alloc((size_t)16777216 * 2);
    float* mulf          = (float*)alloc((size_t)4194304 * 4);
    (void)ws_size; (void)n_in; (void)in_sizes; (void)out_size;

    hipMemsetAsync(zp, 0, 8192, stream);

    // weight prep: w1 LINEAR (conv1 loads to VGPR), w2 swizzled (conv2 LDS)
    wprep_k<128, 512, false><<<2240, 256, 0, stream>>>(mw1, w1m, aw1, w1a, 70);
    wprep_k<512, 128, true ><<<1344, 256, 0, stream>>>(mw2, w2m, aw2, w2a, 42);

    // level-0 split (levels 1,2 are fused into conv2-EPI1)
    split_k<<<4096, 256, 0, stream>>>(x, actb, 512);

    for (int lvl = 0; lvl < 3; ++lvl) {
        const int P = 1 << lvl;
        const int G = 2 * P;
        const int Ls = (1024 >> lvl) >> 1;
        const int idxbase = P - 1;
        const float* cur = (lvl == 0) ? x : ((lvl == 1) ? bufA : bufB);
        float* nxt = (lvl == 1) ? bufB : bufA;
        const int rsplit = (B_ * Ls / 64) / 8;   // 8 row-tiles per block
        const int RT2 = Ls / 2;                  // conv2 64-row tiles

        conv1_k<<<512, 256, 0, stream>>>(actb, w1m, mb1, hidb, zp,
                                         Ls, rsplit, idxbase);
        conv2_k<0><<<G * RT2, 256, 0, stream>>>(hidb, w2m, mb2, cur, mulf,
                                                actb, nullptr, nullptr, nullptr,
                                                zp, Ls, RT2, idxbase);
        conv1_k<<<512, 256, 0, stream>>>(actb, w1a, ab1, hidb, zp,
                                         Ls, rsplit, idxbase);
        if (lvl < 2) {
            conv2_k<1><<<G * RT2, 256, 0, stream>>>(hidb, w2a, ab2, nullptr, mulf,
                                                    nullptr, nxt, actb, nullptr,
                                                    zp, Ls, RT2, idxbase);
        } else {
            conv2_k<2><<<G * RT2, 256, 0, stream>>>(hidb, w2a, ab2, nullptr, mulf,
                                                    nullptr, nullptr, nullptr,
                                                    (float*)d_out,
                                                    zp, Ls, RT2, idxbase);
        }
    }
}